// Round 3
// baseline (108.082 us; speedup 1.0000x reference)
//
#include <hip/hip_runtime.h>

// Conv2d 3x3 s1 p1 NCHW fp32: N=32, Cin=128, H=W=56, Cout=256.
// Round 3: bf16 MFMA implicit GEMM with SPATIALLY PADDED xT.
//   xTp: [n][58][58][ci] bf16, zero borders -> im2col = base + const tap offset
//   (no bounds checks / zero-page in the GEMM hot loop).
//   GEMM: C[co][m], tile 128(co) x 128(m), BK=64, m97 structure,
//   global_load_lds w=16, source-preswizzled chunks (validated 0 conflicts).
//   XCD-aware block swizzle keeps (mblk, cblk-pair) on one XCD.

typedef __attribute__((ext_vector_type(8))) short short8;
typedef __attribute__((ext_vector_type(4))) float float4v;

constexpr int NB = 32, CI = 128, HH = 56, WW = 56, CO = 256;
constexpr int HWP = HH * WW;                 // 3136
constexpr int HP = 58, WP = 58;              // padded spatial dims
constexpr size_t XTP_BYTES = (size_t)NB * HP * WP * CI * 2;   // 27,553,792
constexpr size_t WT_OFF    = XTP_BYTES;
constexpr size_t WT_BYTES  = (size_t)9 * CO * CI * 2;         // 589,824
constexpr size_t WS_NEED   = WT_OFF + WT_BYTES;               // 28,143,616

__device__ inline ushort f2bf(float v) {
    union { float f; uint u; } c; c.f = v;
    uint u = c.u;
    return (ushort)((u + 0x7fffu + ((u >> 16) & 1u)) >> 16);
}

// ---- x: [n][ci][h][w] f32 -> xTp interior: [n][h+1][w+1][ci] bf16 ----
__global__ __launch_bounds__(256) void xform_x(const float* __restrict__ x,
                                               ushort* __restrict__ xTp) {
    int b = blockIdx.x;
    int cit = b & 3;            // 4 ci-tiles of 32
    int hwt = (b >> 2) % 49;    // 49 hw-tiles of 64
    int n   = b / (4 * 49);
    int ci0 = cit * 32, hw0 = hwt * 64;
    __shared__ float t[32][65];
    int tx = threadIdx.x;
    int col = tx & 63, r4 = tx >> 6;
#pragma unroll
    for (int rr = 0; rr < 8; ++rr) {
        int row = rr * 4 + r4;
        t[row][col] = x[((size_t)n * CI + ci0 + row) * HWP + hw0 + col];
    }
    __syncthreads();
    int i = tx & 31, j0 = tx >> 5;
#pragma unroll
    for (int jj = 0; jj < 8; ++jj) {
        int j = jj * 8 + j0;
        int hw = hw0 + j;
        int h = hw / WW, w = hw % WW;
        xTp[(((size_t)n * HP + h + 1) * WP + (w + 1)) * CI + ci0 + i] = f2bf(t[i][j]);
    }
}

// ---- zero-fill the padded borders (1.87 MB) ----
__global__ __launch_bounds__(256) void xform_border(ushort* __restrict__ xTp) {
    int u = blockIdx.x * 256 + threadIdx.x;   // 116736 units of short8
    int ci8 = u & 15;
    int r = u >> 4;            // 7296 = 32 * 228 border cells
    int n = r / 228, bb = r % 228;
    int hp, wp;
    if (bb < 58)       { hp = 0;  wp = bb; }
    else if (bb < 116) { hp = 57; wp = bb - 58; }
    else { int c = bb - 116; hp = 1 + (c >> 1); wp = (c & 1) * 57; }
    short8 z = (short8)0;
    *reinterpret_cast<short8*>(xTp + (((size_t)n * HP + hp) * WP + wp) * CI + ci8 * 8) = z;
}

// ---- w: [co][ci][kh][kw] f32 -> wT: [tap][co][ci] bf16 ----
__global__ __launch_bounds__(256) void xform_w(const float* __restrict__ w,
                                               ushort* __restrict__ wT) {
    int o = blockIdx.x * 256 + threadIdx.x;  // 294912 total
    int ci = o & 127;
    int co = (o >> 7) & 255;
    int tap = o >> 15;
    wT[o] = f2bf(w[((size_t)co * CI + ci) * 9 + tap]);
}

// ---- main implicit GEMM ----
__global__ __launch_bounds__(256) void gemm_conv(
    const ushort* __restrict__ xTp, const ushort* __restrict__ wT,
    const float* __restrict__ bias, float* __restrict__ out)
{
    __shared__ ushort As[128 * 64];  // weights tile [co][ci-chunk], swizzled
    __shared__ ushort Bs[128 * 64];  // im2col tile  [m][ci-chunk],  swizzled

    // XCD swizzle: 1568 blocks, 196 per XCD; keep (mblk, cblk) pairs together,
    // m-contiguous within an XCD. b%8 = XCD under round-robin dispatch.
    int b = blockIdx.x;
    int logical = (b & 7) * 196 + (b >> 3);
    const int mblk = logical >> 1;
    const int cblk = logical & 1;

    const int tid = threadIdx.x, lane = tid & 63, wv = tid >> 6;
    const int wco = wv >> 1, wm = wv & 1;              // 2x2 wave grid
    const int s = (lane & 7) ^ ((lane >> 3) & 7);      // pre-swizzled src chunk

    // per-thread staging element offsets (tap/cb-invariant)
    int aOff[4], bOff[4];
#pragma unroll
    for (int q = 0; q < 4; ++q) {
        int r = wv * 32 + q * 8 + (lane >> 3);
        aOff[q] = (cblk * 128 + r) * CI + s * 8;
        int m = mblk * 128 + r;
        int n = m / HWP, hw = m % HWP, h = hw / WW, w = hw % WW;
        bOff[q] = ((n * HP + h + 1) * WP + (w + 1)) * CI + s * 8;
    }

    float4v acc[4][4];
#pragma unroll
    for (int i = 0; i < 4; ++i)
#pragma unroll
        for (int j = 0; j < 4; ++j) acc[i][j] = (float4v)(0.0f);

    for (int cb = 0; cb < 2; ++cb) {
#pragma unroll 1
        for (int tap = 0; tap < 9; ++tap) {
            const int dh = tap / 3 - 1, dw = tap % 3 - 1;       // scalar
            const int toff = (dh * WP + dw) * CI + cb * 64;     // scalar
            const int atap = tap * CO * CI + cb * 64;           // scalar
#pragma unroll
            for (int q = 0; q < 4; ++q) {
                __builtin_amdgcn_global_load_lds(
                    (const __attribute__((address_space(1))) uint*)(wT + aOff[q] + atap),
                    (__attribute__((address_space(3))) uint*)(As + (wv * 32 + q * 8) * 64),
                    16, 0, 0);
            }
#pragma unroll
            for (int q = 0; q < 4; ++q) {
                __builtin_amdgcn_global_load_lds(
                    (const __attribute__((address_space(1))) uint*)(xTp + bOff[q] + toff),
                    (__attribute__((address_space(3))) uint*)(Bs + (wv * 32 + q * 8) * 64),
                    16, 0, 0);
            }
            __syncthreads();
#pragma unroll
            for (int kk = 0; kk < 2; ++kk) {
                short8 a[4], bfr[4];
#pragma unroll
                for (int f = 0; f < 4; ++f) {
                    int row = wco * 64 + f * 16 + (lane & 15);
                    int ch = (kk * 4 + (lane >> 4)) ^ (row & 7);
                    a[f] = *(const short8*)(As + row * 64 + ch * 8);
                }
#pragma unroll
                for (int f = 0; f < 4; ++f) {
                    int row = wm * 64 + f * 16 + (lane & 15);
                    int ch = (kk * 4 + (lane >> 4)) ^ (row & 7);
                    bfr[f] = *(const short8*)(Bs + row * 64 + ch * 8);
                }
#pragma unroll
                for (int i = 0; i < 4; ++i)
#pragma unroll
                    for (int j = 0; j < 4; ++j)
                        acc[i][j] = __builtin_amdgcn_mfma_f32_16x16x32_bf16(
                            a[i], bfr[j], acc[i][j], 0, 0, 0);
            }
            __syncthreads();
        }
    }

    // epilogue: C[co][m] + bias[co] -> out[n][co][h][w]
    const int co0 = cblk * 128 + wco * 64;
    const int m0  = mblk * 128 + wm * 64;
    float bv[4][4];
#pragma unroll
    for (int i = 0; i < 4; ++i)
#pragma unroll
        for (int r = 0; r < 4; ++r)
            bv[i][r] = bias[co0 + i * 16 + (lane >> 4) * 4 + r];
#pragma unroll
    for (int j = 0; j < 4; ++j) {
        int m = m0 + j * 16 + (lane & 15);
        int n = m / HWP, hw = m % HWP;
        float* obase = out + (size_t)n * CO * HWP + hw;
#pragma unroll
        for (int i = 0; i < 4; ++i) {
            int co = co0 + i * 16 + (lane >> 4) * 4;
#pragma unroll
            for (int r = 0; r < 4; ++r)
                obase[(size_t)(co + r) * HWP] = acc[i][j][r] + bv[i][r];
        }
    }
}

// ---- fallback (round-1 direct conv) if ws too small ----
__global__ __launch_bounds__(256) void conv_k(
    const float* __restrict__ x, const float* __restrict__ wgt,
    const float* __restrict__ bias, float* __restrict__ out)
{
    int idx = blockIdx.x * 256 + threadIdx.x;
    int wg = idx % 14; int t = idx / 14;
    int ho = t % 56; t /= 56;
    int cog = t % 64; int n = t / 64;
    int w0 = wg * 4, co0 = cog * 4;
    float acc[4][4];
#pragma unroll
    for (int j = 0; j < 4; ++j) {
        float bj = bias[co0 + j];
#pragma unroll
        for (int p = 0; p < 4; ++p) acc[j][p] = bj;
    }
    const float* xn = x + (size_t)n * CI * HWP;
    for (int ci = 0; ci < CI; ++ci) {
        float xr[3][6];
#pragma unroll
        for (int kh = 0; kh < 3; ++kh) {
            int hi = ho + kh - 1;
            if (hi >= 0 && hi < HH) {
                const float* row = xn + ((size_t)ci * HH + hi) * WW;
                float4 c = *reinterpret_cast<const float4*>(row + w0);
                xr[kh][1] = c.x; xr[kh][2] = c.y; xr[kh][3] = c.z; xr[kh][4] = c.w;
                xr[kh][0] = (w0 > 0) ? row[w0 - 1] : 0.0f;
                xr[kh][5] = (w0 + 4 < WW) ? row[w0 + 4] : 0.0f;
            } else {
#pragma unroll
                for (int q = 0; q < 6; ++q) xr[kh][q] = 0.0f;
            }
        }
#pragma unroll
        for (int j = 0; j < 4; ++j) {
            const float* wp = wgt + ((size_t)(co0 + j) * CI + ci) * 9;
            float wvv[9];
#pragma unroll
            for (int q = 0; q < 9; ++q) wvv[q] = wp[q];
#pragma unroll
            for (int kh = 0; kh < 3; ++kh)
#pragma unroll
                for (int kw = 0; kw < 3; ++kw)
#pragma unroll
                    for (int p = 0; p < 4; ++p)
                        acc[j][p] = fmaf(xr[kh][p + kw], wvv[kh * 3 + kw], acc[j][p]);
        }
    }
#pragma unroll
    for (int j = 0; j < 4; ++j) {
        float4 v = make_float4(acc[j][0], acc[j][1], acc[j][2], acc[j][3]);
        *reinterpret_cast<float4*>(out + (((size_t)n * CO + co0 + j) * HH + ho) * WW + w0) = v;
    }
}

extern "C" void kernel_launch(void* const* d_in, const int* in_sizes, int n_in,
                              void* d_out, int out_size, void* d_ws, size_t ws_size,
                              hipStream_t stream) {
    const float* x = (const float*)d_in[0];
    const float* w = (const float*)d_in[1];
    const float* b = (const float*)d_in[2];
    float* out = (float*)d_out;

    if (ws_size < WS_NEED) {  // safety fallback
        hipLaunchKernelGGL(conv_k, dim3(6272), dim3(256), 0, stream, x, w, b, out);
        return;
    }

    ushort* xTp = (ushort*)d_ws;
    ushort* wT  = (ushort*)((char*)d_ws + WT_OFF);

    hipLaunchKernelGGL(xform_x, dim3(32 * 49 * 4), dim3(256), 0, stream, x, xTp);
    hipLaunchKernelGGL(xform_border, dim3(456), dim3(256), 0, stream, xTp);
    hipLaunchKernelGGL(xform_w, dim3(9 * CO * CI / 256), dim3(256), 0, stream, w, wT);
    hipLaunchKernelGGL(gemm_conv, dim3(784 * 2), dim3(256), 0, stream,
                       xTp, wT, b, out);
}

// Round 4
// 102.405 us; speedup vs baseline: 1.0554x; 1.0554x over previous
//
#include <hip/hip_runtime.h>

// Conv2d 3x3 s1 p1 NCHW fp32: N=32, Cin=128, H=W=56, Cout=256.
// Round 4: bf16 MFMA implicit GEMM, 2-PHASE double-buffered pipeline (T3-min).
//   xTp: [n][58][58][ci] bf16 zero-padded borders -> tap = const offset.
//   GEMM C[co][m]: tile 128(co)x128(m), BK=64, 18 K-tiles (9 taps x 2 cb).
//   Pipeline: STAGE(t+1 -> other slot) issued BEFORE compute(t); ONE barrier
//   per tile (compiler emits vmcnt(0)+lgkmcnt(0) drain there) -> load latency
//   hides under 16 ds_read_b128 + 32 MFMA. LDS 64KB (2 slots) -> 2 blocks/CU.
//   Staging source pre-swizzled (chunk ^= row&7): 0 bank conflicts (verified).

typedef __attribute__((ext_vector_type(8))) short short8;
typedef __attribute__((ext_vector_type(4))) float float4v;

constexpr int NB = 32, CI = 128, HH = 56, WW = 56, CO = 256;
constexpr int HWP = HH * WW;                 // 3136
constexpr int HP = 58, WP = 58;              // padded spatial dims
constexpr size_t XTP_BYTES = (size_t)NB * HP * WP * CI * 2;   // 27,553,792
constexpr size_t WT_OFF    = XTP_BYTES;
constexpr size_t WT_BYTES  = (size_t)9 * CO * CI * 2;         // 589,824
constexpr size_t WS_NEED   = WT_OFF + WT_BYTES;               // 28,143,616

__device__ inline ushort f2bf(float v) {
    union { float f; uint u; } c; c.f = v;
    uint u = c.u;
    return (ushort)((u + 0x7fffu + ((u >> 16) & 1u)) >> 16);
}

// ---- x: [n][ci][h][w] f32 -> xTp interior: [n][h+1][w+1][ci] bf16 ----
__global__ __launch_bounds__(256) void xform_x(const float* __restrict__ x,
                                               ushort* __restrict__ xTp) {
    int b = blockIdx.x;
    int cit = b & 3;
    int hwt = (b >> 2) % 49;
    int n   = b / (4 * 49);
    int ci0 = cit * 32, hw0 = hwt * 64;
    __shared__ float t[32][65];
    int tx = threadIdx.x;
    int col = tx & 63, r4 = tx >> 6;
#pragma unroll
    for (int rr = 0; rr < 8; ++rr) {
        int row = rr * 4 + r4;
        t[row][col] = x[((size_t)n * CI + ci0 + row) * HWP + hw0 + col];
    }
    __syncthreads();
    int i = tx & 31, j0 = tx >> 5;
#pragma unroll
    for (int jj = 0; jj < 8; ++jj) {
        int j = jj * 8 + j0;
        int hw = hw0 + j;
        int h = hw / WW, w = hw % WW;
        xTp[(((size_t)n * HP + h + 1) * WP + (w + 1)) * CI + ci0 + i] = f2bf(t[i][j]);
    }
}

// ---- zero-fill padded borders ----
__global__ __launch_bounds__(256) void xform_border(ushort* __restrict__ xTp) {
    int u = blockIdx.x * 256 + threadIdx.x;   // 116736 units of short8
    int ci8 = u & 15;
    int r = u >> 4;
    int n = r / 228, bb = r % 228;
    int hp, wp;
    if (bb < 58)       { hp = 0;  wp = bb; }
    else if (bb < 116) { hp = 57; wp = bb - 58; }
    else { int c = bb - 116; hp = 1 + (c >> 1); wp = (c & 1) * 57; }
    short8 z = (short8)0;
    *reinterpret_cast<short8*>(xTp + (((size_t)n * HP + hp) * WP + wp) * CI + ci8 * 8) = z;
}

// ---- w: [co][ci][kh][kw] f32 -> wT: [tap][co][ci] bf16 ----
__global__ __launch_bounds__(256) void xform_w(const float* __restrict__ w,
                                               ushort* __restrict__ wT) {
    int o = blockIdx.x * 256 + threadIdx.x;
    int ci = o & 127;
    int co = (o >> 7) & 255;
    int tap = o >> 15;
    wT[o] = f2bf(w[((size_t)co * CI + ci) * 9 + tap]);
}

// ---- main implicit GEMM, 2-phase pipeline ----
__global__ __launch_bounds__(256) void gemm_conv(
    const ushort* __restrict__ xTp, const ushort* __restrict__ wT,
    const float* __restrict__ bias, float* __restrict__ out)
{
    __shared__ ushort As[2][128 * 64];   // weights, double-buffered (32KB)
    __shared__ ushort Bs[2][128 * 64];   // im2col,  double-buffered (32KB)

    // XCD swizzle: cblk pairs on one XCD, m-contiguous chunks (1568 = 8*196)
    int b = blockIdx.x;
    int logical = (b & 7) * 196 + (b >> 3);
    const int mblk = logical >> 1;
    const int cblk = logical & 1;

    const int tid = threadIdx.x, lane = tid & 63, wv = tid >> 6;
    const int wco = wv >> 1, wm = wv & 1;             // 2x2 wave grid
    const int s = (lane & 7) ^ ((lane >> 3) & 7);     // pre-swizzled src chunk

    // per-thread staging offsets (tile-invariant parts)
    int aOff[4], bOff[4];
#pragma unroll
    for (int q = 0; q < 4; ++q) {
        int r = wv * 32 + q * 8 + (lane >> 3);
        aOff[q] = (cblk * 128 + r) * CI + s * 8;
        int m = mblk * 128 + r;
        int n = m / HWP, hw = m % HWP, h = hw / WW, w = hw % WW;
        bOff[q] = ((n * HP + h + 1) * WP + (w + 1)) * CI + s * 8;
    }

    float4v acc[4][4];
#pragma unroll
    for (int i = 0; i < 4; ++i)
#pragma unroll
        for (int j = 0; j < 4; ++j) acc[i][j] = (float4v)(0.0f);

    // tile t (0..17): tap = t>>1, cb = t&1  (tap-outer -> L1 reuse across cb)
    auto STAGE = [&](int slot, int t) {
        int tap = t >> 1, cb = (t & 1) * 64;
        int dh = tap / 3 - 1, dw = tap % 3 - 1;
        int ao = tap * CO * CI + cb;
        int bo = (dh * WP + dw) * CI + cb;
        ushort* asb = &As[slot][0];
        ushort* bsb = &Bs[slot][0];
#pragma unroll
        for (int q = 0; q < 4; ++q)
            __builtin_amdgcn_global_load_lds(
                (const __attribute__((address_space(1))) uint*)(wT + aOff[q] + ao),
                (__attribute__((address_space(3))) uint*)(asb + (wv * 32 + q * 8) * 64),
                16, 0, 0);
#pragma unroll
        for (int q = 0; q < 4; ++q)
            __builtin_amdgcn_global_load_lds(
                (const __attribute__((address_space(1))) uint*)(xTp + bOff[q] + bo),
                (__attribute__((address_space(3))) uint*)(bsb + (wv * 32 + q * 8) * 64),
                16, 0, 0);
    };

    auto COMPUTE = [&](int slot) {
        const ushort* asb = &As[slot][0];
        const ushort* bsb = &Bs[slot][0];
#pragma unroll
        for (int kk = 0; kk < 2; ++kk) {
            short8 a[4], bf[4];
#pragma unroll
            for (int f = 0; f < 4; ++f) {
                int row = wco * 64 + f * 16 + (lane & 15);
                int ch = (kk * 4 + (lane >> 4)) ^ (row & 7);
                a[f] = *(const short8*)(asb + row * 64 + ch * 8);
            }
#pragma unroll
            for (int f = 0; f < 4; ++f) {
                int row = wm * 64 + f * 16 + (lane & 15);
                int ch = (kk * 4 + (lane >> 4)) ^ (row & 7);
                bf[f] = *(const short8*)(bsb + row * 64 + ch * 8);
            }
#pragma unroll
            for (int i = 0; i < 4; ++i)
#pragma unroll
                for (int j = 0; j < 4; ++j)
                    acc[i][j] = __builtin_amdgcn_mfma_f32_16x16x32_bf16(
                        a[i], bf[j], acc[i][j], 0, 0, 0);
        }
    };

    // prologue: tile 0 -> slot 0
    STAGE(0, 0);
    __syncthreads();                       // vmcnt(0) drain emitted here

    // 8 pairs: tiles 0..15, staging 1..16. ONE barrier per tile.
#pragma unroll 1
    for (int t = 0; t < 16; t += 2) {
        STAGE(1, t + 1);                   // issue next-tile loads FIRST
        COMPUTE(0);                        // compute tile t (slot 0)
        __syncthreads();                   // drain: tile t+1 landed; all waves done with slot 0
        STAGE(0, t + 2);
        COMPUTE(1);                        // tile t+1 (slot 1)
        __syncthreads();
    }
    // tail: slot0 = tile 16
    STAGE(1, 17);
    COMPUTE(0);
    __syncthreads();
    COMPUTE(1);                            // tile 17

    // epilogue: C[co][m] + bias[co] -> out[n][co][h][w]
    const int co0 = cblk * 128 + wco * 64;
    const int m0  = mblk * 128 + wm * 64;
    float bv[4][4];
#pragma unroll
    for (int i = 0; i < 4; ++i)
#pragma unroll
        for (int r = 0; r < 4; ++r)
            bv[i][r] = bias[co0 + i * 16 + (lane >> 4) * 4 + r];
#pragma unroll
    for (int j = 0; j < 4; ++j) {
        int m = m0 + j * 16 + (lane & 15);
        int n = m / HWP, hw = m % HWP;
        float* obase = out + (size_t)n * CO * HWP + hw;
#pragma unroll
        for (int i = 0; i < 4; ++i) {
            int co = co0 + i * 16 + (lane >> 4) * 4;
#pragma unroll
            for (int r = 0; r < 4; ++r)
                obase[(size_t)(co + r) * HWP] = acc[i][j][r] + bv[i][r];
        }
    }
}

// ---- fallback (round-1 direct conv) if ws too small ----
__global__ __launch_bounds__(256) void conv_k(
    const float* __restrict__ x, const float* __restrict__ wgt,
    const float* __restrict__ bias, float* __restrict__ out)
{
    int idx = blockIdx.x * 256 + threadIdx.x;
    int wg = idx % 14; int t = idx / 14;
    int ho = t % 56; t /= 56;
    int cog = t % 64; int n = t / 64;
    int w0 = wg * 4, co0 = cog * 4;
    float acc[4][4];
#pragma unroll
    for (int j = 0; j < 4; ++j) {
        float bj = bias[co0 + j];
#pragma unroll
        for (int p = 0; p < 4; ++p) acc[j][p] = bj;
    }
    const float* xn = x + (size_t)n * CI * HWP;
    for (int ci = 0; ci < CI; ++ci) {
        float xr[3][6];
#pragma unroll
        for (int kh = 0; kh < 3; ++kh) {
            int hi = ho + kh - 1;
            if (hi >= 0 && hi < HH) {
                const float* row = xn + ((size_t)ci * HH + hi) * WW;
                float4 c = *reinterpret_cast<const float4*>(row + w0);
                xr[kh][1] = c.x; xr[kh][2] = c.y; xr[kh][3] = c.z; xr[kh][4] = c.w;
                xr[kh][0] = (w0 > 0) ? row[w0 - 1] : 0.0f;
                xr[kh][5] = (w0 + 4 < WW) ? row[w0 + 4] : 0.0f;
            } else {
#pragma unroll
                for (int q = 0; q < 6; ++q) xr[kh][q] = 0.0f;
            }
        }
#pragma unroll
        for (int j = 0; j < 4; ++j) {
            const float* wp = wgt + ((size_t)(co0 + j) * CI + ci) * 9;
            float wvv[9];
#pragma unroll
            for (int q = 0; q < 9; ++q) wvv[q] = wp[q];
#pragma unroll
            for (int kh = 0; kh < 3; ++kh)
#pragma unroll
                for (int kw = 0; kw < 3; ++kw)
#pragma unroll
                    for (int p = 0; p < 4; ++p)
                        acc[j][p] = fmaf(xr[kh][p + kw], wvv[kh * 3 + kw], acc[j][p]);
        }
    }
#pragma unroll
    for (int j = 0; j < 4; ++j) {
        float4 v = make_float4(acc[j][0], acc[j][1], acc[j][2], acc[j][3]);
        *reinterpret_cast<float4*>(out + (((size_t)n * CO + co0 + j) * HH + ho) * WW + w0) = v;
    }
}

extern "C" void kernel_launch(void* const* d_in, const int* in_sizes, int n_in,
                              void* d_out, int out_size, void* d_ws, size_t ws_size,
                              hipStream_t stream) {
    const float* x = (const float*)d_in[0];
    const float* w = (const float*)d_in[1];
    const float* b = (const float*)d_in[2];
    float* out = (float*)d_out;

    if (ws_size < WS_NEED) {  // safety fallback
        hipLaunchKernelGGL(conv_k, dim3(6272), dim3(256), 0, stream, x, w, b, out);
        return;
    }

    ushort* xTp = (ushort*)d_ws;
    ushort* wT  = (ushort*)((char*)d_ws + WT_OFF);

    hipLaunchKernelGGL(xform_x, dim3(32 * 49 * 4), dim3(256), 0, stream, x, xTp);
    hipLaunchKernelGGL(xform_border, dim3(456), dim3(256), 0, stream, xTp);
    hipLaunchKernelGGL(xform_w, dim3(9 * CO * CI / 256), dim3(256), 0, stream, w, wT);
    hipLaunchKernelGGL(gemm_conv, dim3(784 * 2), dim3(256), 0, stream,
                       xTp, wT, b, out);
}